// Round 1
// baseline (1363.937 us; speedup 1.0000x reference)
//
#include <hip/hip_runtime.h>
#include <math.h>

#define NN 40000
#define EE 640000
#define DD 128
#define EDD 16
#define LL 3

__device__ __constant__ float kBnInv = 0.9999950000374997f; // 1/sqrt(1+1e-5)

// ---------------------------------------------------------------------------
// h = x @ node_W + node_b   ([40000,128] @ [128,128])
// 32 rows per block, 256 threads. x-tile staged in LDS; W read coalesced.
__global__ __launch_bounds__(256) void node_enc_kernel(
    const float* __restrict__ x, const float* __restrict__ W,
    const float* __restrict__ b, float* __restrict__ h)
{
    __shared__ float xs[32][DD];
    const int t = threadIdx.x;
    const long rowbase = (long)blockIdx.x * 32;

    const float4* x4 = (const float4*)(x + rowbase * DD);
    float4* xs4 = (float4*)&xs[0][0];
#pragma unroll
    for (int i = 0; i < 4; i++) xs4[t + i * 256] = x4[t + i * 256];
    __syncthreads();

    const int c  = (t & 31) * 4;   // 32 lanes cover 128 cols (float4 each)
    const int r0 = (t >> 5) * 4;   // 8 groups * 4 rows = 32 rows

    float acc[4][4] = {};
    for (int k = 0; k < DD; k++) {
        const float4 w = *(const float4*)(W + k * DD + c);
#pragma unroll
        for (int i = 0; i < 4; i++) {
            const float xv = xs[r0 + i][k];
            acc[i][0] = fmaf(xv, w.x, acc[i][0]);
            acc[i][1] = fmaf(xv, w.y, acc[i][1]);
            acc[i][2] = fmaf(xv, w.z, acc[i][2]);
            acc[i][3] = fmaf(xv, w.w, acc[i][3]);
        }
    }
    const float4 bv = *(const float4*)(b + c);
#pragma unroll
    for (int i = 0; i < 4; i++) {
        float4 ov = { acc[i][0] + bv.x, acc[i][1] + bv.y,
                      acc[i][2] + bv.z, acc[i][3] + bv.w };
        *(float4*)(h + (rowbase + r0 + i) * DD + c) = ov;
    }
}

// ---------------------------------------------------------------------------
// Fused per-edge pipeline for one layer:
//   e   = edge_attr @ edge_W + edge_b
//   a   = sigmoid([h[dst], h[src]] @ attn_W + attn_b)
//   msg = relu(h[src]*a + e);  atomicAdd(agg[dst], msg)
// One wave per edge, 8 edges per wave (weights held in regs across edges).
// Lane owns cols {lane, lane+64}.
#define EPW 8
__global__ __launch_bounds__(256) void edge_kernel(
    const float* __restrict__ h, const float* __restrict__ edge_attr,
    const float* __restrict__ eW,   // [16][128] for this layer
    const float* __restrict__ eb,   // [128]
    const float* __restrict__ aW,   // [256]
    const float* __restrict__ ab_p, // [1]
    const int* __restrict__ edge_index, float* __restrict__ agg)
{
    const int wid  = threadIdx.x >> 6;
    const int lane = threadIdx.x & 63;
    const int c0 = lane, c1 = lane + 64;

    // per-lane weight slices (amortized over EPW edges)
    float ew0[EDD], ew1[EDD];
#pragma unroll
    for (int k = 0; k < EDD; k++) {
        ew0[k] = eW[k * DD + c0];
        ew1[k] = eW[k * DD + c1];
    }
    const float awi0 = aW[c0],      awi1 = aW[c1];
    const float awj0 = aW[DD + c0], awj1 = aW[DD + c1];
    const float eb0 = eb[c0], eb1 = eb[c1];
    const float ab = ab_p[0];

    const long ebase = (long)(blockIdx.x * 4 + wid) * EPW;
    for (int i = 0; i < EPW; i++) {
        const long e = ebase + i;
        const int src = edge_index[e];
        const int dst = edge_index[EE + e];

        const float4* eap = (const float4*)(edge_attr + e * EDD);
        const float4 t0 = eap[0], t1 = eap[1], t2 = eap[2], t3 = eap[3];
        float ea[EDD] = { t0.x, t0.y, t0.z, t0.w, t1.x, t1.y, t1.z, t1.w,
                          t2.x, t2.y, t2.z, t2.w, t3.x, t3.y, t3.z, t3.w };

        const float* hs = h + (long)src * DD;
        const float* hd = h + (long)dst * DD;
        const float xj0 = hs[c0], xj1 = hs[c1];
        const float xi0 = hd[c0], xi1 = hd[c1];

        float ev0 = eb0, ev1 = eb1;
#pragma unroll
        for (int k = 0; k < EDD; k++) {
            ev0 = fmaf(ea[k], ew0[k], ev0);
            ev1 = fmaf(ea[k], ew1[k], ev1);
        }

        float p = xi0 * awi0 + xi1 * awi1 + xj0 * awj0 + xj1 * awj1;
#pragma unroll
        for (int off = 32; off > 0; off >>= 1) p += __shfl_xor(p, off, 64);
        const float a = 1.0f / (1.0f + expf(-(p + ab)));

        const float m0 = fmaxf(fmaf(xj0, a, ev0), 0.0f);
        const float m1 = fmaxf(fmaf(xj1, a, ev1), 0.0f);
        atomicAdd(&agg[(long)dst * DD + c0], m0);
        atomicAdd(&agg[(long)dst * DD + c1], m1);
    }
}

// ---------------------------------------------------------------------------
// Fused GIN MLP for one layer:
//   z = (1+eps)*h + agg
//   u = relu(bn1(z@W1 + b1));  out = bn2(u@W2 + b2); optional relu
// 16 rows per block, 256 threads, z/u tiles in LDS.
__global__ __launch_bounds__(256) void mlp_kernel(
    const float* __restrict__ h, const float* __restrict__ agg,
    const float* __restrict__ eps_p,
    const float* __restrict__ W1, const float* __restrict__ b1,
    const float* __restrict__ g1, const float* __restrict__ bb1,
    const float* __restrict__ W2, const float* __restrict__ b2,
    const float* __restrict__ g2, const float* __restrict__ bb2,
    float* __restrict__ out, const int do_relu)
{
    __shared__ float zs[16][DD];
    __shared__ float us[16][2 * DD];
    const int t = threadIdx.x;
    const long rowbase = (long)blockIdx.x * 16;
    const float ep = 1.0f + eps_p[0];

    const float4* h4 = (const float4*)(h + rowbase * DD);
    const float4* a4 = (const float4*)(agg + rowbase * DD);
    float4* z4 = (float4*)&zs[0][0];
#pragma unroll
    for (int i = 0; i < 2; i++) {
        const int idx = t + i * 256;
        const float4 hv = h4[idx], av = a4[idx];
        float4 zv = { fmaf(ep, hv.x, av.x), fmaf(ep, hv.y, av.y),
                      fmaf(ep, hv.z, av.z), fmaf(ep, hv.w, av.w) };
        z4[idx] = zv;
    }
    __syncthreads();

    // phase 1: u[16][256] = relu(bn1(z @ W1 + b1))
    {
        const int c  = (t & 63) * 4;   // 64 lanes cover 256 cols
        const int r0 = (t >> 6) * 4;   // wave-uniform row group
        float acc[4][4] = {};
        for (int k = 0; k < DD; k++) {
            const float4 w = *(const float4*)(W1 + k * 2 * DD + c);
#pragma unroll
            for (int i = 0; i < 4; i++) {
                const float zv = zs[r0 + i][k];
                acc[i][0] = fmaf(zv, w.x, acc[i][0]);
                acc[i][1] = fmaf(zv, w.y, acc[i][1]);
                acc[i][2] = fmaf(zv, w.z, acc[i][2]);
                acc[i][3] = fmaf(zv, w.w, acc[i][3]);
            }
        }
        const float4 b1v = *(const float4*)(b1 + c);
        const float4 g1v = *(const float4*)(g1 + c);
        const float4 s1v = *(const float4*)(bb1 + c);
#pragma unroll
        for (int i = 0; i < 4; i++) {
            float4 uv;
            uv.x = fmaxf(fmaf(g1v.x * (acc[i][0] + b1v.x), kBnInv, s1v.x), 0.0f);
            uv.y = fmaxf(fmaf(g1v.y * (acc[i][1] + b1v.y), kBnInv, s1v.y), 0.0f);
            uv.z = fmaxf(fmaf(g1v.z * (acc[i][2] + b1v.z), kBnInv, s1v.z), 0.0f);
            uv.w = fmaxf(fmaf(g1v.w * (acc[i][3] + b1v.w), kBnInv, s1v.w), 0.0f);
            *(float4*)&us[r0 + i][c] = uv;
        }
    }
    __syncthreads();

    // phase 2: out[16][128] = bn2(u @ W2 + b2) (+ relu)
    {
        const int c  = (t & 31) * 4;   // 32 lanes cover 128 cols
        const int r0 = (t >> 5) * 2;   // 8 groups * 2 rows
        float acc[2][4] = {};
        for (int k = 0; k < 2 * DD; k++) {
            const float4 w = *(const float4*)(W2 + k * DD + c);
#pragma unroll
            for (int i = 0; i < 2; i++) {
                const float uv = us[r0 + i][k];
                acc[i][0] = fmaf(uv, w.x, acc[i][0]);
                acc[i][1] = fmaf(uv, w.y, acc[i][1]);
                acc[i][2] = fmaf(uv, w.z, acc[i][2]);
                acc[i][3] = fmaf(uv, w.w, acc[i][3]);
            }
        }
        const float4 b2v = *(const float4*)(b2 + c);
        const float4 g2v = *(const float4*)(g2 + c);
        const float4 s2v = *(const float4*)(bb2 + c);
#pragma unroll
        for (int i = 0; i < 2; i++) {
            float4 ov;
            ov.x = fmaf(g2v.x * (acc[i][0] + b2v.x), kBnInv, s2v.x);
            ov.y = fmaf(g2v.y * (acc[i][1] + b2v.y), kBnInv, s2v.y);
            ov.z = fmaf(g2v.z * (acc[i][2] + b2v.z), kBnInv, s2v.z);
            ov.w = fmaf(g2v.w * (acc[i][3] + b2v.w), kBnInv, s2v.w);
            if (do_relu) {
                ov.x = fmaxf(ov.x, 0.0f); ov.y = fmaxf(ov.y, 0.0f);
                ov.z = fmaxf(ov.z, 0.0f); ov.w = fmaxf(ov.w, 0.0f);
            }
            *(float4*)(out + (rowbase + r0 + i) * DD + c) = ov;
        }
    }
}

// ---------------------------------------------------------------------------
extern "C" void kernel_launch(void* const* d_in, const int* in_sizes, int n_in,
                              void* d_out, int out_size, void* d_ws, size_t ws_size,
                              hipStream_t stream)
{
    const float* x         = (const float*)d_in[0];
    const float* edge_attr = (const float*)d_in[1];
    const float* node_W    = (const float*)d_in[2];
    const float* node_b    = (const float*)d_in[3];
    const float* edge_W    = (const float*)d_in[4];
    const float* edge_b    = (const float*)d_in[5];
    const float* attn_W    = (const float*)d_in[6];
    const float* attn_b    = (const float*)d_in[7];
    const float* eps       = (const float*)d_in[8];
    const float* W1        = (const float*)d_in[9];
    const float* b1        = (const float*)d_in[10];
    const float* bn1_g     = (const float*)d_in[11];
    const float* bn1_b     = (const float*)d_in[12];
    const float* W2        = (const float*)d_in[13];
    const float* b2        = (const float*)d_in[14];
    const float* bn_g      = (const float*)d_in[15];
    const float* bn_b      = (const float*)d_in[16];
    const int*   edge_index= (const int*)d_in[17];

    float* h   = (float*)d_ws;                 // [N,128]
    float* agg = h + (size_t)NN * DD;          // [N,128]
    float* out = (float*)d_out;

    node_enc_kernel<<<NN / 32, 256, 0, stream>>>(x, node_W, node_b, h);

    for (int l = 0; l < LL; l++) {
        hipMemsetAsync(agg, 0, (size_t)NN * DD * sizeof(float), stream);
        edge_kernel<<<EE / (4 * EPW), 256, 0, stream>>>(
            h, edge_attr,
            edge_W + (size_t)l * EDD * DD, edge_b + (size_t)l * DD,
            attn_W + (size_t)l * 2 * DD, attn_b + l,
            edge_index, agg);
        mlp_kernel<<<NN / 16, 256, 0, stream>>>(
            h, agg, eps + l,
            W1 + (size_t)l * DD * 2 * DD, b1 + (size_t)l * 2 * DD,
            bn1_g + (size_t)l * 2 * DD, bn1_b + (size_t)l * 2 * DD,
            W2 + (size_t)l * 2 * DD * DD, b2 + (size_t)l * DD,
            bn_g + (size_t)l * DD, bn_b + (size_t)l * DD,
            (l == LL - 1) ? out : h, (l < LL - 1) ? 1 : 0);
    }
}

// Round 2
// 1144.937 us; speedup vs baseline: 1.1913x; 1.1913x over previous
//
#include <hip/hip_runtime.h>
#include <math.h>

#define NN 40000
#define EE 640000
#define DD 128
#define EDD 16
#define LL 3

__device__ __constant__ float kBnInv = 0.9999950000374997f; // 1/sqrt(1+1e-5)

// ---------------------------------------------------------------------------
// h = x @ node_W + node_b   ([40000,128] @ [128,128])
__global__ __launch_bounds__(256) void node_enc_kernel(
    const float* __restrict__ x, const float* __restrict__ W,
    const float* __restrict__ b, float* __restrict__ h)
{
    __shared__ float xs[32][DD];
    const int t = threadIdx.x;
    const long rowbase = (long)blockIdx.x * 32;

    const float4* x4 = (const float4*)(x + rowbase * DD);
    float4* xs4 = (float4*)&xs[0][0];
#pragma unroll
    for (int i = 0; i < 4; i++) xs4[t + i * 256] = x4[t + i * 256];
    __syncthreads();

    const int c  = (t & 31) * 4;
    const int r0 = (t >> 5) * 4;

    float acc[4][4] = {};
    for (int k = 0; k < DD; k++) {
        const float4 w = *(const float4*)(W + k * DD + c);
#pragma unroll
        for (int i = 0; i < 4; i++) {
            const float xv = xs[r0 + i][k];
            acc[i][0] = fmaf(xv, w.x, acc[i][0]);
            acc[i][1] = fmaf(xv, w.y, acc[i][1]);
            acc[i][2] = fmaf(xv, w.z, acc[i][2]);
            acc[i][3] = fmaf(xv, w.w, acc[i][3]);
        }
    }
    const float4 bv = *(const float4*)(b + c);
#pragma unroll
    for (int i = 0; i < 4; i++) {
        float4 ov = { acc[i][0] + bv.x, acc[i][1] + bv.y,
                      acc[i][2] + bv.z, acc[i][3] + bv.w };
        *(float4*)(h + (rowbase + r0 + i) * DD + c) = ov;
    }
}

// ---------------------------------------------------------------------------
// CSR build: histogram of dst, block-scan, scatter edge ids.
__global__ __launch_bounds__(256) void hist_kernel(
    const int* __restrict__ edge_index, int* __restrict__ counts)
{
    const int i = blockIdx.x * 256 + threadIdx.x;   // grid covers EE exactly
    atomicAdd(&counts[edge_index[EE + i]], 1);
}

// Per-block scan: 40 blocks x 256 thr x 4 items = 40960 >= NN
__global__ __launch_bounds__(256) void scan1_kernel(
    const int* __restrict__ counts, int* __restrict__ scanned,
    int* __restrict__ partials)
{
    __shared__ int sdata[256];
    const int t = threadIdx.x;
    const int base = blockIdx.x * 1024 + t * 4;
    int v[4]; int sum = 0;
#pragma unroll
    for (int i = 0; i < 4; i++) {
        const int idx = base + i;
        v[i] = (idx < NN) ? counts[idx] : 0;
        sum += v[i];
    }
    sdata[t] = sum;
    __syncthreads();
    for (int off = 1; off < 256; off <<= 1) {
        int x = (t >= off) ? sdata[t - off] : 0;
        __syncthreads();
        sdata[t] += x;
        __syncthreads();
    }
    int run = sdata[t] - sum;   // exclusive prefix for this thread
#pragma unroll
    for (int i = 0; i < 4; i++) {
        const int idx = base + i;
        if (idx < NN) scanned[idx] = run;
        run += v[i];
    }
    if (t == 255) partials[blockIdx.x] = sdata[255];
}

__global__ void scan2_kernel(int* __restrict__ partials)
{
    if (threadIdx.x == 0) {
        int run = 0;
        for (int i = 0; i < 40; i++) { int v = partials[i]; partials[i] = run; run += v; }
    }
}

__global__ __launch_bounds__(256) void scan3_kernel(
    const int* __restrict__ scanned, const int* __restrict__ partials,
    int* __restrict__ offsets, int* __restrict__ cursor)
{
    const int idx = blockIdx.x * 256 + threadIdx.x;
    if (idx < NN) {
        const int off = scanned[idx] + partials[idx >> 10];
        offsets[idx] = off;
        cursor[idx]  = off;
    }
}

__global__ __launch_bounds__(256) void scatter_kernel(
    const int* __restrict__ edge_index, int* __restrict__ cursor,
    int* __restrict__ perm)
{
    const int i = blockIdx.x * 256 + threadIdx.x;
    const int pos = atomicAdd(&cursor[edge_index[EE + i]], 1);
    perm[pos] = i;
}

// ---------------------------------------------------------------------------
// Dst-centric fused edge pipeline for one layer. One wave per node.
//   for each in-edge e (src j):
//     ev  = edge_attr[e] @ edge_W + edge_b
//     a   = sigmoid(h[n]·aW_i + h[j]·aW_j + ab)
//     acc += relu(h[j]*a + ev)
//   z[n] = (1+eps)*h[n] + acc
__global__ __launch_bounds__(256) void edge_agg_kernel(
    const float* __restrict__ h, const float* __restrict__ edge_attr,
    const float* __restrict__ eW, const float* __restrict__ eb,
    const float* __restrict__ aW, const float* __restrict__ ab_p,
    const float* __restrict__ eps_p,
    const int* __restrict__ edge_src,           // edge_index row 0
    const int* __restrict__ perm,
    const int* __restrict__ offsets, const int* __restrict__ counts,
    float* __restrict__ z)
{
    const int wid  = threadIdx.x >> 6;
    const int lane = threadIdx.x & 63;
    const int n = blockIdx.x * 4 + wid;          // grid = NN/4 exactly
    const int c0 = lane, c1 = lane + 64;

    float ew0[EDD], ew1[EDD];
#pragma unroll
    for (int k = 0; k < EDD; k++) {
        ew0[k] = eW[k * DD + c0];
        ew1[k] = eW[k * DD + c1];
    }
    const float awi0 = aW[c0],      awi1 = aW[c1];
    const float awj0 = aW[DD + c0], awj1 = aW[DD + c1];
    const float eb0 = eb[c0], eb1 = eb[c1];
    const float ab = ab_p[0];
    const float ep = 1.0f + eps_p[0];

    const float xi0 = h[(long)n * DD + c0];
    const float xi1 = h[(long)n * DD + c1];

    float pi = xi0 * awi0 + xi1 * awi1;
#pragma unroll
    for (int off = 32; off > 0; off >>= 1) pi += __shfl_xor(pi, off, 64);
    pi += ab;

    float acc0 = 0.0f, acc1 = 0.0f;
    const int s   = offsets[n];
    const int cnt = counts[n];

    for (int k = 0; k < cnt; k++) {
        const int e   = perm[s + k];
        const int src = edge_src[e];

        const float4* eap = (const float4*)(edge_attr + (long)e * EDD);
        const float4 t0 = eap[0], t1 = eap[1], t2 = eap[2], t3 = eap[3];
        const float ea[EDD] = { t0.x, t0.y, t0.z, t0.w, t1.x, t1.y, t1.z, t1.w,
                                t2.x, t2.y, t2.z, t2.w, t3.x, t3.y, t3.z, t3.w };

        const float* hs = h + (long)src * DD;
        const float xj0 = hs[c0], xj1 = hs[c1];

        float ev0 = eb0, ev1 = eb1;
#pragma unroll
        for (int q = 0; q < EDD; q++) {
            ev0 = fmaf(ea[q], ew0[q], ev0);
            ev1 = fmaf(ea[q], ew1[q], ev1);
        }

        float pj = xj0 * awj0 + xj1 * awj1;
#pragma unroll
        for (int off = 32; off > 0; off >>= 1) pj += __shfl_xor(pj, off, 64);
        const float a = 1.0f / (1.0f + expf(-(pi + pj)));

        acc0 += fmaxf(fmaf(xj0, a, ev0), 0.0f);
        acc1 += fmaxf(fmaf(xj1, a, ev1), 0.0f);
    }

    z[(long)n * DD + c0] = fmaf(ep, xi0, acc0);
    z[(long)n * DD + c1] = fmaf(ep, xi1, acc1);
}

// ---------------------------------------------------------------------------
// Fused GIN MLP: u = relu(bn1(z@W1+b1)); out = bn2(u@W2+b2) (+relu)
__global__ __launch_bounds__(256) void mlp_kernel(
    const float* __restrict__ zin,
    const float* __restrict__ W1, const float* __restrict__ b1,
    const float* __restrict__ g1, const float* __restrict__ bb1,
    const float* __restrict__ W2, const float* __restrict__ b2,
    const float* __restrict__ g2, const float* __restrict__ bb2,
    float* __restrict__ out, const int do_relu)
{
    __shared__ float zs[16][DD];
    __shared__ float us[16][2 * DD];
    const int t = threadIdx.x;
    const long rowbase = (long)blockIdx.x * 16;

    const float4* z4in = (const float4*)(zin + rowbase * DD);
    float4* z4 = (float4*)&zs[0][0];
#pragma unroll
    for (int i = 0; i < 2; i++) {
        const int idx = t + i * 256;
        z4[idx] = z4in[idx];
    }
    __syncthreads();

    {
        const int c  = (t & 63) * 4;
        const int r0 = (t >> 6) * 4;
        float acc[4][4] = {};
        for (int k = 0; k < DD; k++) {
            const float4 w = *(const float4*)(W1 + k * 2 * DD + c);
#pragma unroll
            for (int i = 0; i < 4; i++) {
                const float zv = zs[r0 + i][k];
                acc[i][0] = fmaf(zv, w.x, acc[i][0]);
                acc[i][1] = fmaf(zv, w.y, acc[i][1]);
                acc[i][2] = fmaf(zv, w.z, acc[i][2]);
                acc[i][3] = fmaf(zv, w.w, acc[i][3]);
            }
        }
        const float4 b1v = *(const float4*)(b1 + c);
        const float4 g1v = *(const float4*)(g1 + c);
        const float4 s1v = *(const float4*)(bb1 + c);
#pragma unroll
        for (int i = 0; i < 4; i++) {
            float4 uv;
            uv.x = fmaxf(fmaf(g1v.x * (acc[i][0] + b1v.x), kBnInv, s1v.x), 0.0f);
            uv.y = fmaxf(fmaf(g1v.y * (acc[i][1] + b1v.y), kBnInv, s1v.y), 0.0f);
            uv.z = fmaxf(fmaf(g1v.z * (acc[i][2] + b1v.z), kBnInv, s1v.z), 0.0f);
            uv.w = fmaxf(fmaf(g1v.w * (acc[i][3] + b1v.w), kBnInv, s1v.w), 0.0f);
            *(float4*)&us[r0 + i][c] = uv;
        }
    }
    __syncthreads();

    {
        const int c  = (t & 31) * 4;
        const int r0 = (t >> 5) * 2;
        float acc[2][4] = {};
        for (int k = 0; k < 2 * DD; k++) {
            const float4 w = *(const float4*)(W2 + k * DD + c);
#pragma unroll
            for (int i = 0; i < 2; i++) {
                const float uv = us[r0 + i][k];
                acc[i][0] = fmaf(uv, w.x, acc[i][0]);
                acc[i][1] = fmaf(uv, w.y, acc[i][1]);
                acc[i][2] = fmaf(uv, w.z, acc[i][2]);
                acc[i][3] = fmaf(uv, w.w, acc[i][3]);
            }
        }
        const float4 b2v = *(const float4*)(b2 + c);
        const float4 g2v = *(const float4*)(g2 + c);
        const float4 s2v = *(const float4*)(bb2 + c);
#pragma unroll
        for (int i = 0; i < 2; i++) {
            float4 ov;
            ov.x = fmaf(g2v.x * (acc[i][0] + b2v.x), kBnInv, s2v.x);
            ov.y = fmaf(g2v.y * (acc[i][1] + b2v.y), kBnInv, s2v.y);
            ov.z = fmaf(g2v.z * (acc[i][2] + b2v.z), kBnInv, s2v.z);
            ov.w = fmaf(g2v.w * (acc[i][3] + b2v.w), kBnInv, s2v.w);
            if (do_relu) {
                ov.x = fmaxf(ov.x, 0.0f); ov.y = fmaxf(ov.y, 0.0f);
                ov.z = fmaxf(ov.z, 0.0f); ov.w = fmaxf(ov.w, 0.0f);
            }
            *(float4*)(out + (rowbase + r0 + i) * DD + c) = ov;
        }
    }
}

// ---------------------------------------------------------------------------
extern "C" void kernel_launch(void* const* d_in, const int* in_sizes, int n_in,
                              void* d_out, int out_size, void* d_ws, size_t ws_size,
                              hipStream_t stream)
{
    const float* x         = (const float*)d_in[0];
    const float* edge_attr = (const float*)d_in[1];
    const float* node_W    = (const float*)d_in[2];
    const float* node_b    = (const float*)d_in[3];
    const float* edge_W    = (const float*)d_in[4];
    const float* edge_b    = (const float*)d_in[5];
    const float* attn_W    = (const float*)d_in[6];
    const float* attn_b    = (const float*)d_in[7];
    const float* eps       = (const float*)d_in[8];
    const float* W1        = (const float*)d_in[9];
    const float* b1        = (const float*)d_in[10];
    const float* bn1_g     = (const float*)d_in[11];
    const float* bn1_b     = (const float*)d_in[12];
    const float* W2        = (const float*)d_in[13];
    const float* b2        = (const float*)d_in[14];
    const float* bn_g      = (const float*)d_in[15];
    const float* bn_b      = (const float*)d_in[16];
    const int*   edge_index= (const int*)d_in[17];

    // workspace layout
    float* h = (float*)d_ws;                         // [N*D]
    float* z = h + (size_t)NN * DD;                  // [N*D]
    int* ibase   = (int*)(z + (size_t)NN * DD);
    int* counts  = ibase;                            // [N]
    int* offsets = counts + NN;                      // [N]
    int* cursor  = offsets + NN;                     // [N]
    int* scanned = cursor + NN;                      // [40960]
    int* partials= scanned + 40960;                  // [64]
    int* perm    = partials + 64;                    // [E]
    float* out = (float*)d_out;

    node_enc_kernel<<<NN / 32, 256, 0, stream>>>(x, node_W, node_b, h);

    // Build CSR (dst -> in-edge list) once; reused by all 3 layers.
    hipMemsetAsync(counts, 0, NN * sizeof(int), stream);
    hist_kernel<<<EE / 256, 256, 0, stream>>>(edge_index, counts);
    scan1_kernel<<<40, 256, 0, stream>>>(counts, scanned, partials);
    scan2_kernel<<<1, 64, 0, stream>>>(partials);
    scan3_kernel<<<(NN + 255) / 256, 256, 0, stream>>>(scanned, partials, offsets, cursor);
    scatter_kernel<<<EE / 256, 256, 0, stream>>>(edge_index, cursor, perm);

    for (int l = 0; l < LL; l++) {
        edge_agg_kernel<<<NN / 4, 256, 0, stream>>>(
            h, edge_attr,
            edge_W + (size_t)l * EDD * DD, edge_b + (size_t)l * DD,
            attn_W + (size_t)l * 2 * DD, attn_b + l, eps + l,
            edge_index, perm, offsets, counts, z);
        mlp_kernel<<<NN / 16, 256, 0, stream>>>(
            z,
            W1 + (size_t)l * DD * 2 * DD, b1 + (size_t)l * 2 * DD,
            bn1_g + (size_t)l * 2 * DD, bn1_b + (size_t)l * 2 * DD,
            W2 + (size_t)l * 2 * DD * DD, b2 + (size_t)l * DD,
            bn_g + (size_t)l * DD, bn_b + (size_t)l * DD,
            (l == LL - 1) ? out : h, (l < LL - 1) ? 1 : 0);
    }
}

// Round 3
// 1057.824 us; speedup vs baseline: 1.2894x; 1.0824x over previous
//
#include <hip/hip_runtime.h>
#include <math.h>

#define NN 40000
#define EE 640000
#define DD 128
#define EDD 16
#define LL 3

__device__ __constant__ float kBnInv = 0.9999950000374997f; // 1/sqrt(1+1e-5)

// ---------------------------------------------------------------------------
// h = x @ node_W + node_b   ([40000,128] @ [128,128])
__global__ __launch_bounds__(256) void node_enc_kernel(
    const float* __restrict__ x, const float* __restrict__ W,
    const float* __restrict__ b, float* __restrict__ h)
{
    __shared__ float xs[32][DD];
    const int t = threadIdx.x;
    const long rowbase = (long)blockIdx.x * 32;

    const float4* x4 = (const float4*)(x + rowbase * DD);
    float4* xs4 = (float4*)&xs[0][0];
#pragma unroll
    for (int i = 0; i < 4; i++) xs4[t + i * 256] = x4[t + i * 256];
    __syncthreads();

    const int c  = (t & 31) * 4;
    const int r0 = (t >> 5) * 4;

    float acc[4][4] = {};
    for (int k4 = 0; k4 < DD; k4 += 4) {
        float4 xr[4];
#pragma unroll
        for (int i = 0; i < 4; i++) xr[i] = *(const float4*)&xs[r0 + i][k4];
#pragma unroll
        for (int kk = 0; kk < 4; kk++) {
            const float4 w = *(const float4*)(W + (k4 + kk) * DD + c);
#pragma unroll
            for (int i = 0; i < 4; i++) {
                const float xv = ((const float*)&xr[i])[kk];
                acc[i][0] = fmaf(xv, w.x, acc[i][0]);
                acc[i][1] = fmaf(xv, w.y, acc[i][1]);
                acc[i][2] = fmaf(xv, w.z, acc[i][2]);
                acc[i][3] = fmaf(xv, w.w, acc[i][3]);
            }
        }
    }
    const float4 bv = *(const float4*)(b + c);
#pragma unroll
    for (int i = 0; i < 4; i++) {
        float4 ov = { acc[i][0] + bv.x, acc[i][1] + bv.y,
                      acc[i][2] + bv.z, acc[i][3] + bv.w };
        *(float4*)(h + (rowbase + r0 + i) * DD + c) = ov;
    }
}

// ---------------------------------------------------------------------------
// CSR build
__global__ __launch_bounds__(256) void hist_kernel(
    const int* __restrict__ edge_index, int* __restrict__ counts)
{
    const int i = blockIdx.x * 256 + threadIdx.x;
    atomicAdd(&counts[edge_index[EE + i]], 1);
}

__global__ __launch_bounds__(256) void scan1_kernel(
    const int* __restrict__ counts, int* __restrict__ scanned,
    int* __restrict__ partials)
{
    __shared__ int sdata[256];
    const int t = threadIdx.x;
    const int base = blockIdx.x * 1024 + t * 4;
    int v[4]; int sum = 0;
#pragma unroll
    for (int i = 0; i < 4; i++) {
        const int idx = base + i;
        v[i] = (idx < NN) ? counts[idx] : 0;
        sum += v[i];
    }
    sdata[t] = sum;
    __syncthreads();
    for (int off = 1; off < 256; off <<= 1) {
        int x = (t >= off) ? sdata[t - off] : 0;
        __syncthreads();
        sdata[t] += x;
        __syncthreads();
    }
    int run = sdata[t] - sum;
#pragma unroll
    for (int i = 0; i < 4; i++) {
        const int idx = base + i;
        if (idx < NN) scanned[idx] = run;
        run += v[i];
    }
    if (t == 255) partials[blockIdx.x] = sdata[255];
}

__global__ void scan2_kernel(int* __restrict__ partials)
{
    if (threadIdx.x == 0) {
        int run = 0;
        for (int i = 0; i < 40; i++) { int v = partials[i]; partials[i] = run; run += v; }
    }
}

__global__ __launch_bounds__(256) void scan3_kernel(
    const int* __restrict__ scanned, const int* __restrict__ partials,
    int* __restrict__ offsets, int* __restrict__ cursor)
{
    const int idx = blockIdx.x * 256 + threadIdx.x;
    if (idx < NN) {
        const int off = scanned[idx] + partials[idx >> 10];
        offsets[idx] = off;
        cursor[idx]  = off;
    }
}

// writes perm + permuted src/dst arrays
__global__ __launch_bounds__(256) void scatter_kernel(
    const int* __restrict__ edge_index, int* __restrict__ cursor,
    int* __restrict__ perm, int* __restrict__ src_p, int* __restrict__ dst_p)
{
    const int i = blockIdx.x * 256 + threadIdx.x;
    const int src = edge_index[i];
    const int dst = edge_index[EE + i];
    const int pos = atomicAdd(&cursor[dst], 1);
    perm[pos] = i;
    src_p[pos] = src;
    dst_p[pos] = dst;
}

// permute edge_attr into CSR order (once; reused by all layers)
__global__ __launch_bounds__(256) void ea_perm_kernel(
    const float* __restrict__ edge_attr, const int* __restrict__ perm,
    float* __restrict__ ea_p)
{
    const int pos = blockIdx.x * 256 + threadIdx.x;
    const int e = perm[pos];
    const float4* sp = (const float4*)(edge_attr + (long)e * EDD);
    float4* dp = (float4*)(ea_p + (long)pos * EDD);
    dp[0] = sp[0]; dp[1] = sp[1]; dp[2] = sp[2]; dp[3] = sp[3];
}

// ---------------------------------------------------------------------------
// per-node attention partials: pi[n] = h[n]·aW[0:128], pj[n] = h[n]·aW[128:256]
__global__ __launch_bounds__(256) void attn_pre_kernel(
    const float* __restrict__ h, const float* __restrict__ aW,
    float* __restrict__ pi, float* __restrict__ pj)
{
    const int wid  = threadIdx.x >> 6;
    const int lane = threadIdx.x & 63;
    const int n = blockIdx.x * 4 + wid;
    const int c0 = lane, c1 = lane + 64;
    const float h0 = h[(long)n * DD + c0], h1 = h[(long)n * DD + c1];
    float a = h0 * aW[c0]      + h1 * aW[c1];
    float b = h0 * aW[DD + c0] + h1 * aW[DD + c1];
#pragma unroll
    for (int off = 32; off > 0; off >>= 1) {
        a += __shfl_xor(a, off, 64);
        b += __shfl_xor(b, off, 64);
    }
    if (lane == 0) { pi[n] = a; pj[n] = b; }
}

// per-edge attention coefficient in CSR order
__global__ __launch_bounds__(256) void attn_edge_kernel(
    const float* __restrict__ pi, const float* __restrict__ pj,
    const int* __restrict__ src_p, const int* __restrict__ dst_p,
    const float* __restrict__ ab_p, float* __restrict__ a_p)
{
    const int idx = blockIdx.x * 256 + threadIdx.x;
    const float s = pi[dst_p[idx]] + pj[src_p[idx]] + ab_p[0];
    a_p[idx] = 1.0f / (1.0f + expf(-s));
}

// ---------------------------------------------------------------------------
// Dst-centric aggregation, attention precomputed, edge data in CSR order.
__global__ __launch_bounds__(256) void edge_agg_kernel(
    const float* __restrict__ h, const float* __restrict__ ea_p,
    const float* __restrict__ a_p, const int* __restrict__ src_p,
    const int* __restrict__ offsets, const int* __restrict__ counts,
    const float* __restrict__ eW, const float* __restrict__ eb,
    const float* __restrict__ eps_p, float* __restrict__ z)
{
    const int wid  = threadIdx.x >> 6;
    const int lane = threadIdx.x & 63;
    const int n = blockIdx.x * 4 + wid;
    const int c0 = lane, c1 = lane + 64;

    float ew0[EDD], ew1[EDD];
#pragma unroll
    for (int k = 0; k < EDD; k++) {
        ew0[k] = eW[k * DD + c0];
        ew1[k] = eW[k * DD + c1];
    }
    const float eb0 = eb[c0], eb1 = eb[c1];
    const float ep = 1.0f + eps_p[0];

    const float xi0 = h[(long)n * DD + c0];
    const float xi1 = h[(long)n * DD + c1];

    float acc0 = 0.0f, acc1 = 0.0f;
    const int s   = offsets[n];
    const int cnt = counts[n];

#pragma unroll 2
    for (int k = 0; k < cnt; k++) {
        const long pos = s + k;
        const int src = src_p[pos];
        const float a = a_p[pos];

        const float4* eap = (const float4*)(ea_p + pos * EDD);
        const float4 t0 = eap[0], t1 = eap[1], t2 = eap[2], t3 = eap[3];
        const float ea[EDD] = { t0.x, t0.y, t0.z, t0.w, t1.x, t1.y, t1.z, t1.w,
                                t2.x, t2.y, t2.z, t2.w, t3.x, t3.y, t3.z, t3.w };

        const float* hs = h + (long)src * DD;
        const float xj0 = hs[c0], xj1 = hs[c1];

        float ev0 = eb0, ev1 = eb1;
#pragma unroll
        for (int q = 0; q < EDD; q++) {
            ev0 = fmaf(ea[q], ew0[q], ev0);
            ev1 = fmaf(ea[q], ew1[q], ev1);
        }

        acc0 += fmaxf(fmaf(xj0, a, ev0), 0.0f);
        acc1 += fmaxf(fmaf(xj1, a, ev1), 0.0f);
    }

    z[(long)n * DD + c0] = fmaf(ep, xi0, acc0);
    z[(long)n * DD + c1] = fmaf(ep, xi1, acc1);
}

// ---------------------------------------------------------------------------
// Fused GIN MLP, 32 rows/block, K unrolled x4 with b128 LDS reads.
__global__ __launch_bounds__(256) void mlp_kernel(
    const float* __restrict__ zin,
    const float* __restrict__ W1, const float* __restrict__ b1,
    const float* __restrict__ g1, const float* __restrict__ bb1,
    const float* __restrict__ W2, const float* __restrict__ b2,
    const float* __restrict__ g2, const float* __restrict__ bb2,
    float* __restrict__ out, const int do_relu)
{
    __shared__ float zs[32][DD];
    __shared__ float us[32][2 * DD];
    const int t = threadIdx.x;
    const long rowbase = (long)blockIdx.x * 32;

    const float4* z4in = (const float4*)(zin + rowbase * DD);
    float4* z4 = (float4*)&zs[0][0];
#pragma unroll
    for (int i = 0; i < 4; i++) z4[t + i * 256] = z4in[t + i * 256];
    __syncthreads();

    // phase 1: us[32][256] = relu(bn1(z @ W1 + b1)); 8 rows per thread
    {
        const int c  = (t & 63) * 4;
        const int r0 = (t >> 6) * 8;
        float acc[8][4] = {};
        for (int k4 = 0; k4 < DD; k4 += 4) {
            float4 zr[8];
#pragma unroll
            for (int i = 0; i < 8; i++) zr[i] = *(const float4*)&zs[r0 + i][k4];
#pragma unroll
            for (int kk = 0; kk < 4; kk++) {
                const float4 w = *(const float4*)(W1 + (k4 + kk) * 2 * DD + c);
#pragma unroll
                for (int i = 0; i < 8; i++) {
                    const float zv = ((const float*)&zr[i])[kk];
                    acc[i][0] = fmaf(zv, w.x, acc[i][0]);
                    acc[i][1] = fmaf(zv, w.y, acc[i][1]);
                    acc[i][2] = fmaf(zv, w.z, acc[i][2]);
                    acc[i][3] = fmaf(zv, w.w, acc[i][3]);
                }
            }
        }
        const float4 b1v = *(const float4*)(b1 + c);
        const float4 g1v = *(const float4*)(g1 + c);
        const float4 s1v = *(const float4*)(bb1 + c);
#pragma unroll
        for (int i = 0; i < 8; i++) {
            float4 uv;
            uv.x = fmaxf(fmaf(g1v.x * (acc[i][0] + b1v.x), kBnInv, s1v.x), 0.0f);
            uv.y = fmaxf(fmaf(g1v.y * (acc[i][1] + b1v.y), kBnInv, s1v.y), 0.0f);
            uv.z = fmaxf(fmaf(g1v.z * (acc[i][2] + b1v.z), kBnInv, s1v.z), 0.0f);
            uv.w = fmaxf(fmaf(g1v.w * (acc[i][3] + b1v.w), kBnInv, s1v.w), 0.0f);
            *(float4*)&us[r0 + i][c] = uv;
        }
    }
    __syncthreads();

    // phase 2: out[32][128] = bn2(u @ W2 + b2) (+relu); 4 rows per thread
    {
        const int c  = (t & 31) * 4;
        const int r0 = (t >> 5) * 4;
        float acc[4][4] = {};
        for (int k4 = 0; k4 < 2 * DD; k4 += 4) {
            float4 ur[4];
#pragma unroll
            for (int i = 0; i < 4; i++) ur[i] = *(const float4*)&us[r0 + i][k4];
#pragma unroll
            for (int kk = 0; kk < 4; kk++) {
                const float4 w = *(const float4*)(W2 + (k4 + kk) * DD + c);
#pragma unroll
                for (int i = 0; i < 4; i++) {
                    const float uv = ((const float*)&ur[i])[kk];
                    acc[i][0] = fmaf(uv, w.x, acc[i][0]);
                    acc[i][1] = fmaf(uv, w.y, acc[i][1]);
                    acc[i][2] = fmaf(uv, w.z, acc[i][2]);
                    acc[i][3] = fmaf(uv, w.w, acc[i][3]);
                }
            }
        }
        const float4 b2v = *(const float4*)(b2 + c);
        const float4 g2v = *(const float4*)(g2 + c);
        const float4 s2v = *(const float4*)(bb2 + c);
#pragma unroll
        for (int i = 0; i < 4; i++) {
            float4 ov;
            ov.x = fmaf(g2v.x * (acc[i][0] + b2v.x), kBnInv, s2v.x);
            ov.y = fmaf(g2v.y * (acc[i][1] + b2v.y), kBnInv, s2v.y);
            ov.z = fmaf(g2v.z * (acc[i][2] + b2v.z), kBnInv, s2v.z);
            ov.w = fmaf(g2v.w * (acc[i][3] + b2v.w), kBnInv, s2v.w);
            if (do_relu) {
                ov.x = fmaxf(ov.x, 0.0f); ov.y = fmaxf(ov.y, 0.0f);
                ov.z = fmaxf(ov.z, 0.0f); ov.w = fmaxf(ov.w, 0.0f);
            }
            *(float4*)(out + (rowbase + r0 + i) * DD + c) = ov;
        }
    }
}

// ---------------------------------------------------------------------------
extern "C" void kernel_launch(void* const* d_in, const int* in_sizes, int n_in,
                              void* d_out, int out_size, void* d_ws, size_t ws_size,
                              hipStream_t stream)
{
    const float* x         = (const float*)d_in[0];
    const float* edge_attr = (const float*)d_in[1];
    const float* node_W    = (const float*)d_in[2];
    const float* node_b    = (const float*)d_in[3];
    const float* edge_W    = (const float*)d_in[4];
    const float* edge_b    = (const float*)d_in[5];
    const float* attn_W    = (const float*)d_in[6];
    const float* attn_b    = (const float*)d_in[7];
    const float* eps       = (const float*)d_in[8];
    const float* W1        = (const float*)d_in[9];
    const float* b1        = (const float*)d_in[10];
    const float* bn1_g     = (const float*)d_in[11];
    const float* bn1_b     = (const float*)d_in[12];
    const float* W2        = (const float*)d_in[13];
    const float* b2        = (const float*)d_in[14];
    const float* bn_g      = (const float*)d_in[15];
    const float* bn_b      = (const float*)d_in[16];
    const int*   edge_index= (const int*)d_in[17];

    // workspace layout (floats first, then ints)
    float* h    = (float*)d_ws;                     // [N*D]
    float* z    = h + (size_t)NN * DD;              // [N*D]
    float* pi   = z + (size_t)NN * DD;              // [N]
    float* pj   = pi + NN;                          // [N]
    float* a_p  = pj + NN;                          // [E]
    float* ea_p = a_p + EE;                         // [E*16]
    int* counts  = (int*)(ea_p + (size_t)EE * EDD); // [N]
    int* offsets = counts + NN;                     // [N]
    int* cursor  = offsets + NN;                    // [N]
    int* scanned = cursor + NN;                     // [40960]
    int* partials= scanned + 40960;                 // [64]
    int* perm    = partials + 64;                   // [E]
    int* src_p   = perm + EE;                       // [E]
    int* dst_p   = src_p + EE;                      // [E]
    float* out = (float*)d_out;

    node_enc_kernel<<<NN / 32, 256, 0, stream>>>(x, node_W, node_b, h);

    hipMemsetAsync(counts, 0, NN * sizeof(int), stream);
    hist_kernel<<<EE / 256, 256, 0, stream>>>(edge_index, counts);
    scan1_kernel<<<40, 256, 0, stream>>>(counts, scanned, partials);
    scan2_kernel<<<1, 64, 0, stream>>>(partials);
    scan3_kernel<<<(NN + 255) / 256, 256, 0, stream>>>(scanned, partials, offsets, cursor);
    scatter_kernel<<<EE / 256, 256, 0, stream>>>(edge_index, cursor, perm, src_p, dst_p);
    ea_perm_kernel<<<EE / 256, 256, 0, stream>>>(edge_attr, perm, ea_p);

    for (int l = 0; l < LL; l++) {
        attn_pre_kernel<<<NN / 4, 256, 0, stream>>>(h, attn_W + (size_t)l * 2 * DD, pi, pj);
        attn_edge_kernel<<<EE / 256, 256, 0, stream>>>(pi, pj, src_p, dst_p, attn_b + l, a_p);
        edge_agg_kernel<<<NN / 4, 256, 0, stream>>>(
            h, ea_p, a_p, src_p, offsets, counts,
            edge_W + (size_t)l * EDD * DD, edge_b + (size_t)l * DD, eps + l, z);
        mlp_kernel<<<NN / 32, 256, 0, stream>>>(
            z,
            W1 + (size_t)l * DD * 2 * DD, b1 + (size_t)l * 2 * DD,
            bn1_g + (size_t)l * 2 * DD, bn1_b + (size_t)l * 2 * DD,
            W2 + (size_t)l * 2 * DD * DD, b2 + (size_t)l * DD,
            bn_g + (size_t)l * DD, bn_b + (size_t)l * DD,
            (l == LL - 1) ? out : h, (l < LL - 1) ? 1 : 0);
    }
}